// Round 15
// baseline (219.580 us; speedup 1.0000x reference)
//
#include <hip/hip_runtime.h>
#include <hip/hip_bf16.h>
#include <cstdint>
#include <cstddef>

#define NENT 100000
#define NREL 100
#define DD   128
#define KK   64
#define BB   8192

typedef __bf16 bf16x8 __attribute__((ext_vector_type(8)));
typedef float  f32x4  __attribute__((ext_vector_type(4)));
typedef unsigned int u32x4 __attribute__((ext_vector_type(4)));

__device__ __forceinline__ unsigned short f2bf(float x) {
    union { float f; unsigned u; } v; v.f = x;
    unsigned r = v.u + 0x7fffu + ((v.u >> 16) & 1u);
    return (unsigned short)(r >> 16);
}
__device__ __forceinline__ float bf2f(unsigned short h) {
    union { unsigned u; float f; } v; v.u = ((unsigned)h) << 16;
    return v.f;
}
__device__ __forceinline__ float leakyf(float x) { return x >= 0.f ? x : 0.2f * x; }
__device__ __forceinline__ float sigmoidf(float x) { return 1.f / (1.f + __expf(-x)); }
__device__ __forceinline__ f32x4 mfma16(bf16x8 a, bf16x8 b, f32x4 c) {
    return __builtin_amdgcn_mfma_f32_16x16x32_bf16(a, b, c, 0, 0, 0);
}

// ---------------- prep kernels ----------------

__global__ __launch_bounds__(256) void prep_emb(const float* __restrict__ src,
                                                unsigned short* __restrict__ dst,
                                                int rows) {
    const int lane = threadIdx.x & 63;
    const int row  = blockIdx.x * 4 + (threadIdx.x >> 6);
    if (row >= rows) return;
    const float2 v = *(const float2*)(src + (size_t)row * DD + 2 * lane);
    float sq = v.x * v.x + v.y * v.y;
#pragma unroll
    for (int off = 32; off; off >>= 1) sq += __shfl_xor(sq, off);
    const float n = sqrtf(sq);
    const float s = n > 1.f ? 1.f / (n + 1e-7f) : 1.f;
    unsigned int pk = (unsigned)f2bf(v.x * s) | ((unsigned)f2bf(v.y * s) << 16);
    *(unsigned int*)(dst + (size_t)row * DD + 2 * lane) = pk;
}

__global__ __launch_bounds__(256) void prep_w(
    const float* __restrict__ Wa1, const float* __restrict__ Wa2,
    const float* __restrict__ Wx, const float* __restrict__ W1, const float* __restrict__ W2,
    unsigned short* __restrict__ Wa1b, unsigned short* __restrict__ Wa2b,
    unsigned short* __restrict__ Wxb, unsigned short* __restrict__ W1b,
    unsigned short* __restrict__ W2b) {
    int i = blockIdx.x * 256 + threadIdx.x;
    if (i < 32768)        Wa1b[i]          = f2bf(Wa1[i]);
    else if (i < 49152)   Wa2b[i - 32768]  = f2bf(Wa2[i - 32768]);
    else if (i < 81920)   Wxb[i - 49152]   = f2bf(Wx[i - 49152]);
    else if (i < 147456)  W1b[i - 81920]   = f2bf(W1[i - 81920]);
    else if (i < 212992)  W2b[i - 147456]  = f2bf(W2[i - 147456]);
}

// relP[r][d] = sum_j renorm(rel[r])[j] * Wa1[d][128+j]   (f32 math, bf16 out)
__global__ __launch_bounds__(128) void relp_k(const float* __restrict__ relE,
                                              const float* __restrict__ Wa1f,
                                              unsigned short* __restrict__ relPb) {
    __shared__ float rl[DD];
    __shared__ float red[2];
    const int r = blockIdx.x, d = threadIdx.x, lane = d & 63, wv = d >> 6;
    const float v = relE[(size_t)r * DD + d];
    float sq = v * v;
#pragma unroll
    for (int off = 32; off; off >>= 1) sq += __shfl_xor(sq, off);
    if (lane == 0) red[wv] = sq;
    __syncthreads();
    const float n = sqrtf(red[0] + red[1]);
    const float scl = n > 1.f ? 1.f / (n + 1e-7f) : 1.f;
    rl[d] = v * scl;
    __syncthreads();
    float acc = 0.f;
#pragma unroll 4
    for (int j = 0; j < DD; ++j) acc += rl[j] * Wa1f[(size_t)d * 256 + DD + j];
    relPb[(size_t)r * DD + d] = f2bf(acc);
}

// HH[s][:] = h_s @ Wa1[:, :128]^T   (batched MFMA GEMM, 64 samples/block)
__global__ __launch_bounds__(256) void hh_gemm(
    const int* __restrict__ u1, const int* __restrict__ u2, const int* __restrict__ cI,
    const unsigned short* __restrict__ entB,
    const unsigned short* __restrict__ Wa1b,
    float* __restrict__ HHo) {
    constexpr int AS = 136;
    __shared__ __align__(16) unsigned short AL[64 * AS];
    __shared__ int eL[64];
    const int t = threadIdx.x, lane = t & 63, w = t >> 6, g = lane >> 4, li = lane & 15;
    const int m0 = blockIdx.x * 64;
    const int branch = m0 >> 13, b0 = m0 & (BB - 1);
    const int* ep = branch == 0 ? u1 : branch == 1 ? u2 : cI;
    if (t < 64) eL[t] = ep[b0 + t];
    __syncthreads();
    for (int idx = t; idx < 4096; idx += 256) {
        const int row = idx >> 6, cc = idx & 63;
        *(unsigned int*)&AL[row * AS + cc * 2] =
            ((const unsigned int*)(entB + (size_t)eL[row] * DD))[cc];
    }
    __syncthreads();
    f32x4 acc[4][2] = {};
#pragma unroll
    for (int ks = 0; ks < 4; ++ks) {
        const int kb = ks * 32 + g * 8;
        const bf16x8 bw0 = *(const bf16x8*)(Wa1b + (size_t)((w * 2 + 0) * 16 + li) * 256 + kb);
        const bf16x8 bw1 = *(const bf16x8*)(Wa1b + (size_t)((w * 2 + 1) * 16 + li) * 256 + kb);
#pragma unroll
        for (int mt = 0; mt < 4; ++mt) {
            const bf16x8 a = *(const bf16x8*)(&AL[(mt * 16 + li) * AS + kb]);
            acc[mt][0] = mfma16(a, bw0, acc[mt][0]);
            acc[mt][1] = mfma16(a, bw1, acc[mt][1]);
        }
    }
#pragma unroll
    for (int mt = 0; mt < 4; ++mt)
#pragma unroll
        for (int ntl = 0; ntl < 2; ++ntl) {
            const int col = (w * 2 + ntl) * 16 + li;
#pragma unroll
            for (int i = 0; i < 4; ++i) {
                const int row = mt * 16 + g * 4 + i;
                HHo[(size_t)(m0 + row) * DD + col] = acc[mt][ntl][i];
            }
        }
}

// ---------------- fused attention + tail kernel (512 threads) ----------------
// 1 sample per wave, 8 waves/block sharing one 32KB swizzled Wa2 copy.
// Swapped GEMM2 (D = Wa2 . A1^T). Tail gathers split 8+8: first half issued
// BEFORE GEMM2 (hidden under MFMA+LDS), second half after (hidden under
// reduce+softmax). launch_bounds(512,3) gives ~170-VGPR budget for tv+afr.

__global__ __launch_bounds__(512, 3) void attn_tail(
    const int* __restrict__ u1, const int* __restrict__ u2, const int* __restrict__ cI,
    const int* __restrict__ adj_e, const int* __restrict__ adj_r,
    const unsigned short* __restrict__ entB,
    const unsigned short* __restrict__ relPb,
    const unsigned short* __restrict__ Wa2b,
    const float* __restrict__ Wa3,
    const float* __restrict__ HHp,
    unsigned short* __restrict__ s_bf) {
    __shared__ __align__(16) unsigned short WL[DD * DD];  // 32768 B, swizzled

    const int t = threadIdx.x;
    const int lane = t & 63, w = t >> 6;        // w in [0,8)
    const int g = lane >> 4, li = lane & 15;

    // stage Wa2 with 16B-block XOR swizzle: block' = block ^ (row&15)
    {
        const unsigned int* src = (const unsigned int*)Wa2b;
        unsigned int* dst = (unsigned int*)WL;
#pragma unroll
        for (int it = 0; it < 16; ++it) {
            const int i = t + it * 512;
            const int d = i >> 6, c2 = i & 63;
            const int B = c2 >> 2, j2 = c2 & 3;
            dst[d * 64 + (((B ^ (d & 15))) << 2) + j2] = src[i];
        }
    }

    const int s = blockIdx.x * 8 + w;
    const int branch = s >> 13, b = s & (BB - 1);
    const int e = (branch == 0 ? u1 : branch == 1 ? u2 : cI)[b];
    const int tIr = adj_e[(size_t)e * KK + lane];
    const int rIr = adj_r[(size_t)e * KK + lane];

    int rr4[4];
#pragma unroll
    for (int bt = 0; bt < 4; ++bt) rr4[bt] = __shfl(rIr, bt * 16 + li);

    // hh in even/odd packed f32x4 form
    f32x4 he[4], ho[4];
#pragma unroll
    for (int ks = 0; ks < 4; ++ks) {
        const float* p = HHp + (size_t)s * DD + ks * 32 + g * 8;
        const f32x4 a = *(const f32x4*)p;
        const f32x4 bq = *(const f32x4*)(p + 4);
        he[ks] = (f32x4){a[0], a[2], bq[0], bq[2]};
        ho[ks] = (f32x4){a[1], a[3], bq[1], bq[3]};
    }

    // build A1 fragments (lane (g,li) holds neighbor bt*16+li, dims ks*32+g*8..+8)
    bf16x8 afr[4][4];
#pragma unroll
    for (int bt = 0; bt < 4; ++bt) {
        const unsigned short* pr = relPb + ((size_t)rr4[bt] << 7) + (g << 3);
#pragma unroll
        for (int ks = 0; ks < 4; ++ks) {
            const u32x4 pw = *(const u32x4*)(pr + (ks << 5));
            f32x4 pe, po;
#pragma unroll
            for (int j = 0; j < 4; ++j) {
                pe[j] = __uint_as_float(pw[j] << 16);
                po[j] = __uint_as_float(pw[j] & 0xffff0000u);
            }
            pe += he[ks];
            po += ho[ks];
#pragma unroll
            for (int j = 0; j < 4; ++j) {
                afr[bt][ks][2 * j]     = (__bf16)fmaxf(pe[j], 0.f);
                afr[bt][ks][2 * j + 1] = (__bf16)fmaxf(po[j], 0.f);
            }
        }
    }

    __syncthreads();

    // ---- ISSUE first half of tail gathers (mt=0,1); GEMM2 hides latency ----
    bf16x8 tv[16];
#pragma unroll
    for (int mt = 0; mt < 2; ++mt)
#pragma unroll
        for (int i = 0; i < 4; ++i) {
            const int r = mt * 16 + g * 4 + i;
            const int ti = __shfl(tIr, r);
            tv[mt * 4 + i] = *(const bf16x8*)(entB + (size_t)ti * DD + li * 8);
        }

    // GEMM2 swapped: D[e, k_n] = Wa2 . A1^T; fuse Wa3-dot lane-locally.
    f32x4 pd2 = {};
    const int wrow = li << 7;  // li*128 u16
#pragma unroll
    for (int nt = 0; nt < 8; ++nt) {
        bf16x8 bfr[4];
#pragma unroll
        for (int ks = 0; ks < 4; ++ks)
            bfr[ks] = *(const bf16x8*)(&WL[(nt << 11) + wrow + (((ks * 4 + g) ^ li) << 3)]);
        const f32x4 w3f = *(const f32x4*)(Wa3 + nt * 16 + g * 4);
        f32x4 acc[4] = {};
#pragma unroll
        for (int ks = 0; ks < 4; ++ks)
#pragma unroll
            for (int bt = 0; bt < 4; ++bt) acc[bt] = mfma16(bfr[ks], afr[bt][ks], acc[bt]);
#pragma unroll
        for (int bt = 0; bt < 4; ++bt) {
            pd2[bt] += fmaxf(acc[bt][0], 0.f) * w3f[0] + fmaxf(acc[bt][1], 0.f) * w3f[1] +
                       fmaxf(acc[bt][2], 0.f) * w3f[2] + fmaxf(acc[bt][3], 0.f) * w3f[3];
        }
    }

    // ---- ISSUE second half of tail gathers (mt=2,3) ----
#pragma unroll
    for (int mt = 2; mt < 4; ++mt)
#pragma unroll
        for (int i = 0; i < 4; ++i) {
            const int r = mt * 16 + g * 4 + i;
            const int ti = __shfl(tIr, r);
            tv[mt * 4 + i] = *(const bf16x8*)(entB + (size_t)ti * DD + li * 8);
        }

    // reduce over g (rows split across g) -> every lane holds a3[k=bt*16+li]
#pragma unroll
    for (int bt = 0; bt < 4; ++bt) {
        pd2[bt] += __shfl_xor(pd2[bt], 16);
        pd2[bt] += __shfl_xor(pd2[bt], 32);
    }

    // softmax over sigmoid(a3); sigmoid in (0,1) -> no max needed
    float avn[4];
    float sm = 0.f;
#pragma unroll
    for (int bt = 0; bt < 4; ++bt) {
        avn[bt] = __expf(sigmoidf(pd2[bt]));
        sm += avn[bt];
    }
#pragma unroll
    for (int off = 1; off < 16; off <<= 1) sm += __shfl_xor(sm, off);
    const float inv = 1.f / sm;
    float ws4[4];
#pragma unroll
    for (int bt = 0; bt < 4; ++bt) ws4[bt] = avn[bt] * inv;

    // ---- CONSUME prefetched rows ----
    float s8[8] = {0.f};
#pragma unroll
    for (int mt = 0; mt < 4; ++mt)
#pragma unroll
        for (int i = 0; i < 4; ++i) {
            const float wt = __shfl(ws4[mt], g * 4 + i);
            const bf16x8 t8 = tv[mt * 4 + i];
#pragma unroll
            for (int j = 0; j < 8; ++j) s8[j] += wt * (float)t8[j];
        }
#pragma unroll
    for (int j = 0; j < 8; ++j) {
        s8[j] += __shfl_xor(s8[j], 16);
        s8[j] += __shfl_xor(s8[j], 32);
    }
    if (lane < 16) {
        union { bf16x8 v; unsigned short u[8]; } sv;
#pragma unroll
        for (int j = 0; j < 8; ++j) sv.u[j] = f2bf(s8[j]);
        *(bf16x8*)(s_bf + (size_t)s * DD + li * 8) = sv.v;
    }
}

// ---------------- heads + aggregator + FINAL, fused ----------------
// 512 blocks, 256 threads. Block handles 16 samples x 3 branches (48 rows);
// branch == mt-tile, so max/dot/sigmoid finishes in-block. No agg_ws.

__global__ __launch_bounds__(256, 2) void head_agg3(
    const int* __restrict__ u1, const int* __restrict__ u2, const int* __restrict__ cI,
    const unsigned short* __restrict__ s_bf, const unsigned short* __restrict__ entB,
    const unsigned short* __restrict__ Wxb, const float* __restrict__ bx,
    const unsigned short* __restrict__ W1b, const float* __restrict__ b1,
    const unsigned short* __restrict__ W2b, const float* __restrict__ b2,
    float* __restrict__ out) {
    constexpr int SBS = 136, HS = 132, YS = 264;
    __shared__ __align__(16) unsigned short SB[48 * SBS];
    __shared__ __align__(16) unsigned short HLb[48 * HS];
    __shared__ __align__(16) unsigned short Y1[48 * YS];
    __shared__ __align__(16) unsigned short Y2[48 * YS];
    __shared__ unsigned short bxl[256], b1l[256], b2l[256];
    __shared__ int eL[48];
    __shared__ float prr[4][16];

    const int t = threadIdx.x;
    const int lane = t & 63, w = t >> 6;
    const int g = lane >> 4, li = lane & 15;
    const int m0 = blockIdx.x * 16;

    if (t < 48) {
        const int br = t >> 4, j = t & 15;
        eL[t] = (br == 0 ? u1 : br == 1 ? u2 : cI)[m0 + j];
    }
    bxl[t] = f2bf(bx[t]); b1l[t] = f2bf(b1[t]); b2l[t] = f2bf(b2[t]);
    __syncthreads();

    // stage SB (attention sums) and HLb (renormed h) for 48 rows
    for (int idx = t; idx < 3072; idx += 256) {
        const int row = idx >> 6, cc = idx & 63;
        const int br = row >> 4, j = row & 15;
        const size_t sidx = (size_t)br * BB + m0 + j;
        *(unsigned int*)&SB[row * SBS + cc * 2] =
            ((const unsigned int*)(s_bf + sidx * DD))[cc];
        *(unsigned int*)&HLb[row * HS + cc * 2] =
            ((const unsigned int*)(entB + (size_t)eL[row] * DD))[cc];
    }
    __syncthreads();

    // heads: [48][256] = S[48][128] @ WxFlat^T  (mt = branch)
    f32x4 ah[3][4] = {};
#pragma unroll
    for (int ks = 0; ks < 4; ++ks) {
        const int kb = ks * 32 + g * 8;
        bf16x8 bb[4];
#pragma unroll
        for (int ntl = 0; ntl < 4; ++ntl)
            bb[ntl] = *(const bf16x8*)(Wxb + ((size_t)(w * 4 + ntl) * 16 + li) * DD + kb);
#pragma unroll
        for (int mt = 0; mt < 3; ++mt) {
            const bf16x8 a = *(const bf16x8*)(&SB[(mt * 16 + li) * SBS + kb]);
#pragma unroll
            for (int ntl = 0; ntl < 4; ++ntl) ah[mt][ntl] = mfma16(a, bb[ntl], ah[mt][ntl]);
        }
    }
#pragma unroll
    for (int mt = 0; mt < 3; ++mt)
#pragma unroll
        for (int ntl = 0; ntl < 4; ++ntl) {
            const int col = (w * 4 + ntl) * 16 + li;
            const int ee = col & 127;
#pragma unroll
            for (int i = 0; i < 4; ++i) {
                const int row = mt * 16 + g * 4 + i;
                const float v = ah[mt][ntl][i] + bf2f(bxl[col]);
                const float vec = leakyf(v);
                const float hvv = bf2f(HLb[row * HS + ee]);
                Y1[row * YS + col] = f2bf(hvv + vec);
                Y2[row * YS + col] = f2bf(hvv * vec);
            }
        }
    __syncthreads();

    f32x4 ac1[3][4] = {}, ac2[3][4] = {};
#pragma unroll
    for (int ks = 0; ks < 8; ++ks) {
        const int kb = ks * 32 + g * 8;
        bf16x8 bb1[4], bb2[4];
#pragma unroll
        for (int ntl = 0; ntl < 4; ++ntl) {
            bb1[ntl] = *(const bf16x8*)(W1b + ((size_t)(w * 4 + ntl) * 16 + li) * 256 + kb);
            bb2[ntl] = *(const bf16x8*)(W2b + ((size_t)(w * 4 + ntl) * 16 + li) * 256 + kb);
        }
#pragma unroll
        for (int mt = 0; mt < 3; ++mt) {
            const bf16x8 a1 = *(const bf16x8*)(&Y1[(mt * 16 + li) * YS + kb]);
            const bf16x8 a2 = *(const bf16x8*)(&Y2[(mt * 16 + li) * YS + kb]);
#pragma unroll
            for (int ntl = 0; ntl < 4; ++ntl) {
                ac1[mt][ntl] = mfma16(a1, bb1[ntl], ac1[mt][ntl]);
                ac2[mt][ntl] = mfma16(a2, bb2[ntl], ac2[mt][ntl]);
            }
        }
    }

    // agg-part of final dot: thread holds sample j=g*4+i, branch mt, 4 cols
    float part[4] = {0.f, 0.f, 0.f, 0.f};
#pragma unroll
    for (int ntl = 0; ntl < 4; ++ntl) {
        const int col = (w * 4 + ntl) * 16 + li;
        const float bb1v = bf2f(b1l[col]), bb2v = bf2f(b2l[col]);
#pragma unroll
        for (int i = 0; i < 4; ++i) {
            const float x0 = leakyf(ac1[0][ntl][i] + bb1v) + leakyf(ac2[0][ntl][i] + bb2v);
            const float x1 = leakyf(ac1[1][ntl][i] + bb1v) + leakyf(ac2[1][ntl][i] + bb2v);
            const float x2 = leakyf(ac1[2][ntl][i] + bb1v) + leakyf(ac2[2][ntl][i] + bb2v);
            part[i] += fmaxf(x0, x1) * x2;
        }
    }
#pragma unroll
    for (int off = 1; off < 16; off <<= 1)
#pragma unroll
        for (int i = 0; i < 4; ++i) part[i] += __shfl_xor(part[i], off);
    if (li == 0) {
#pragma unroll
        for (int i = 0; i < 4; ++i) prr[w][g * 4 + i] = part[i];
    }
    __syncthreads();

    // h-part + combine: 16 threads per sample j (t = j*16 + (t&15))
    {
        const int j = t >> 4, dl = (t & 15) * 8;
        const unsigned short* h1p = &HLb[(0 * 16 + j) * HS + dl];
        const unsigned short* h2p = &HLb[(1 * 16 + j) * HS + dl];
        const unsigned short* hcp = &HLb[(2 * 16 + j) * HS + dl];
        float a = 0.f;
#pragma unroll
        for (int jj = 0; jj < 8; ++jj)
            a += fmaxf(bf2f(h1p[jj]), bf2f(h2p[jj])) * bf2f(hcp[jj]);
#pragma unroll
        for (int off = 1; off < 16; off <<= 1) a += __shfl_xor(a, off);
        if ((t & 15) == 0) {
            const float tot = prr[0][j] + prr[1][j] + prr[2][j] + prr[3][j] + a;
            out[m0 + j] = sigmoidf(tot);
        }
    }
}

// ---------------- launcher ----------------

extern "C" void kernel_launch(void* const* d_in, const int* in_sizes, int n_in,
                              void* d_out, int out_size, void* d_ws, size_t ws_size,
                              hipStream_t stream) {
    (void)in_sizes; (void)n_in; (void)out_size; (void)ws_size;
    const int*   u1   = (const int*)d_in[0];
    const int*   u2   = (const int*)d_in[1];
    const int*   cI   = (const int*)d_in[2];
    const int*   adjE = (const int*)d_in[3];
    const int*   adjR = (const int*)d_in[4];
    const float* entE = (const float*)d_in[5];
    const float* relE = (const float*)d_in[6];
    const float* Wa1  = (const float*)d_in[7];
    const float* Wa2  = (const float*)d_in[8];
    const float* Wa3  = (const float*)d_in[9];
    const float* Wx   = (const float*)d_in[10];
    const float* bx   = (const float*)d_in[11];
    const float* W1   = (const float*)d_in[12];
    const float* b1   = (const float*)d_in[13];
    const float* W2   = (const float*)d_in[14];
    const float* b2   = (const float*)d_in[15];
    float* out = (float*)d_out;

    char* ws = (char*)d_ws;
    unsigned short* entB = (unsigned short*)(ws);              // 25,600,000 B
    unsigned short* Wa1b = (unsigned short*)(ws + 25600000);   //     65,536 B
    unsigned short* Wa2b = (unsigned short*)(ws + 25665536);   //     32,768 B
    unsigned short* Wxb  = (unsigned short*)(ws + 25698304);   //     65,536 B
    unsigned short* W1b  = (unsigned short*)(ws + 25763840);   //    131,072 B
    unsigned short* W2b  = (unsigned short*)(ws + 25894912);   //    131,072 B
    unsigned short* relPb = (unsigned short*)(ws + 26025984);  //     25,600 B
    float* HHp   = (float*)(ws + 26051584);                    // 12,582,912 B
    unsigned short* s_bf = (unsigned short*)(ws + 44925952);   //  6,291,456 B
    // total 51,217,408 B

    hipLaunchKernelGGL(prep_emb, dim3(NENT / 4), dim3(256), 0, stream, entE, entB, NENT);
    hipLaunchKernelGGL(prep_w, dim3(832), dim3(256), 0, stream, Wa1, Wa2, Wx, W1, W2,
                       Wa1b, Wa2b, Wxb, W1b, W2b);
    hipLaunchKernelGGL(relp_k, dim3(NREL), dim3(128), 0, stream, relE, Wa1, relPb);
    hipLaunchKernelGGL(hh_gemm, dim3(3 * BB / 64), dim3(256), 0, stream,
                       u1, u2, cI, entB, Wa1b, HHp);
    hipLaunchKernelGGL(attn_tail, dim3(3 * BB / 8), dim3(512), 0, stream,
                       u1, u2, cI, adjE, adjR, entB, relPb, Wa2b, Wa3, HHp, s_bf);
    hipLaunchKernelGGL(head_agg3, dim3(BB / 16), dim3(256), 0, stream,
                       u1, u2, cI, s_bf, entB, Wxb, bx, W1b, b1, W2b, b2, out);
}

// Round 16
// 176.455 us; speedup vs baseline: 1.2444x; 1.2444x over previous
//
#include <hip/hip_runtime.h>
#include <hip/hip_bf16.h>
#include <cstdint>
#include <cstddef>

#define NENT 100000
#define NREL 100
#define DD   128
#define KK   64
#define BB   8192

typedef __bf16 bf16x8 __attribute__((ext_vector_type(8)));
typedef float  f32x4  __attribute__((ext_vector_type(4)));
typedef unsigned int u32x4 __attribute__((ext_vector_type(4)));

__device__ __forceinline__ unsigned short f2bf(float x) {
    union { float f; unsigned u; } v; v.f = x;
    unsigned r = v.u + 0x7fffu + ((v.u >> 16) & 1u);
    return (unsigned short)(r >> 16);
}
__device__ __forceinline__ float bf2f(unsigned short h) {
    union { unsigned u; float f; } v; v.u = ((unsigned)h) << 16;
    return v.f;
}
__device__ __forceinline__ float leakyf(float x) { return x >= 0.f ? x : 0.2f * x; }
__device__ __forceinline__ float sigmoidf(float x) { return 1.f / (1.f + __expf(-x)); }
__device__ __forceinline__ f32x4 mfma16(bf16x8 a, bf16x8 b, f32x4 c) {
    return __builtin_amdgcn_mfma_f32_16x16x32_bf16(a, b, c, 0, 0, 0);
}

// ---------------- prep kernels ----------------

__global__ __launch_bounds__(256) void prep_emb(const float* __restrict__ src,
                                                unsigned short* __restrict__ dst,
                                                int rows) {
    const int lane = threadIdx.x & 63;
    const int row  = blockIdx.x * 4 + (threadIdx.x >> 6);
    if (row >= rows) return;
    const float2 v = *(const float2*)(src + (size_t)row * DD + 2 * lane);
    float sq = v.x * v.x + v.y * v.y;
#pragma unroll
    for (int off = 32; off; off >>= 1) sq += __shfl_xor(sq, off);
    const float n = sqrtf(sq);
    const float s = n > 1.f ? 1.f / (n + 1e-7f) : 1.f;
    unsigned int pk = (unsigned)f2bf(v.x * s) | ((unsigned)f2bf(v.y * s) << 16);
    *(unsigned int*)(dst + (size_t)row * DD + 2 * lane) = pk;
}

__global__ __launch_bounds__(256) void prep_w(
    const float* __restrict__ Wa1, const float* __restrict__ Wa2,
    const float* __restrict__ Wx, const float* __restrict__ W1, const float* __restrict__ W2,
    unsigned short* __restrict__ Wa1b, unsigned short* __restrict__ Wa2b,
    unsigned short* __restrict__ Wxb, unsigned short* __restrict__ W1b,
    unsigned short* __restrict__ W2b) {
    int i = blockIdx.x * 256 + threadIdx.x;
    if (i < 32768)        Wa1b[i]          = f2bf(Wa1[i]);
    else if (i < 49152)   Wa2b[i - 32768]  = f2bf(Wa2[i - 32768]);
    else if (i < 81920)   Wxb[i - 49152]   = f2bf(Wx[i - 49152]);
    else if (i < 147456)  W1b[i - 81920]   = f2bf(W1[i - 81920]);
    else if (i < 212992)  W2b[i - 147456]  = f2bf(W2[i - 147456]);
}

// relP[r][d] = sum_j renorm(rel[r])[j] * Wa1[d][128+j]   (f32 math, bf16 out)
__global__ __launch_bounds__(128) void relp_k(const float* __restrict__ relE,
                                              const float* __restrict__ Wa1f,
                                              unsigned short* __restrict__ relPb) {
    __shared__ float rl[DD];
    __shared__ float red[2];
    const int r = blockIdx.x, d = threadIdx.x, lane = d & 63, wv = d >> 6;
    const float v = relE[(size_t)r * DD + d];
    float sq = v * v;
#pragma unroll
    for (int off = 32; off; off >>= 1) sq += __shfl_xor(sq, off);
    if (lane == 0) red[wv] = sq;
    __syncthreads();
    const float n = sqrtf(red[0] + red[1]);
    const float scl = n > 1.f ? 1.f / (n + 1e-7f) : 1.f;
    rl[d] = v * scl;
    __syncthreads();
    float acc = 0.f;
#pragma unroll 4
    for (int j = 0; j < DD; ++j) acc += rl[j] * Wa1f[(size_t)d * 256 + DD + j];
    relPb[(size_t)r * DD + d] = f2bf(acc);
}

// HH[s][:] = h_s @ Wa1[:, :128]^T   (batched MFMA GEMM, 64 samples/block)
__global__ __launch_bounds__(256) void hh_gemm(
    const int* __restrict__ u1, const int* __restrict__ u2, const int* __restrict__ cI,
    const unsigned short* __restrict__ entB,
    const unsigned short* __restrict__ Wa1b,
    float* __restrict__ HHo) {
    constexpr int AS = 136;
    __shared__ __align__(16) unsigned short AL[64 * AS];
    __shared__ int eL[64];
    const int t = threadIdx.x, lane = t & 63, w = t >> 6, g = lane >> 4, li = lane & 15;
    const int m0 = blockIdx.x * 64;
    const int branch = m0 >> 13, b0 = m0 & (BB - 1);
    const int* ep = branch == 0 ? u1 : branch == 1 ? u2 : cI;
    if (t < 64) eL[t] = ep[b0 + t];
    __syncthreads();
    for (int idx = t; idx < 4096; idx += 256) {
        const int row = idx >> 6, cc = idx & 63;
        *(unsigned int*)&AL[row * AS + cc * 2] =
            ((const unsigned int*)(entB + (size_t)eL[row] * DD))[cc];
    }
    __syncthreads();
    f32x4 acc[4][2] = {};
#pragma unroll
    for (int ks = 0; ks < 4; ++ks) {
        const int kb = ks * 32 + g * 8;
        const bf16x8 bw0 = *(const bf16x8*)(Wa1b + (size_t)((w * 2 + 0) * 16 + li) * 256 + kb);
        const bf16x8 bw1 = *(const bf16x8*)(Wa1b + (size_t)((w * 2 + 1) * 16 + li) * 256 + kb);
#pragma unroll
        for (int mt = 0; mt < 4; ++mt) {
            const bf16x8 a = *(const bf16x8*)(&AL[(mt * 16 + li) * AS + kb]);
            acc[mt][0] = mfma16(a, bw0, acc[mt][0]);
            acc[mt][1] = mfma16(a, bw1, acc[mt][1]);
        }
    }
#pragma unroll
    for (int mt = 0; mt < 4; ++mt)
#pragma unroll
        for (int ntl = 0; ntl < 2; ++ntl) {
            const int col = (w * 2 + ntl) * 16 + li;
#pragma unroll
            for (int i = 0; i < 4; ++i) {
                const int row = mt * 16 + g * 4 + i;
                HHo[(size_t)(m0 + row) * DD + col] = acc[mt][ntl][i];
            }
        }
}

// ---------------- fused attention + tail kernel (512 threads) ----------------
// (round-14 proven best: swapped GEMM2, gathers issued after GEMM2, (512,4))

__global__ __launch_bounds__(512, 4) void attn_tail(
    const int* __restrict__ u1, const int* __restrict__ u2, const int* __restrict__ cI,
    const int* __restrict__ adj_e, const int* __restrict__ adj_r,
    const unsigned short* __restrict__ entB,
    const unsigned short* __restrict__ relPb,
    const unsigned short* __restrict__ Wa2b,
    const float* __restrict__ Wa3,
    const float* __restrict__ HHp,
    unsigned short* __restrict__ s_bf) {
    __shared__ __align__(16) unsigned short WL[DD * DD];  // 32768 B, swizzled

    const int t = threadIdx.x;
    const int lane = t & 63, w = t >> 6;        // w in [0,8)
    const int g = lane >> 4, li = lane & 15;

    // stage Wa2 with 16B-block XOR swizzle: block' = block ^ (row&15)
    {
        const unsigned int* src = (const unsigned int*)Wa2b;
        unsigned int* dst = (unsigned int*)WL;
#pragma unroll
        for (int it = 0; it < 16; ++it) {
            const int i = t + it * 512;
            const int d = i >> 6, c2 = i & 63;
            const int B = c2 >> 2, j2 = c2 & 3;
            dst[d * 64 + (((B ^ (d & 15))) << 2) + j2] = src[i];
        }
    }

    const int s = blockIdx.x * 8 + w;
    const int branch = s >> 13, b = s & (BB - 1);
    const int e = (branch == 0 ? u1 : branch == 1 ? u2 : cI)[b];
    const int tIr = adj_e[(size_t)e * KK + lane];
    const int rIr = adj_r[(size_t)e * KK + lane];

    int rr4[4];
#pragma unroll
    for (int bt = 0; bt < 4; ++bt) rr4[bt] = __shfl(rIr, bt * 16 + li);

    // hh in even/odd packed f32x4 form
    f32x4 he[4], ho[4];
#pragma unroll
    for (int ks = 0; ks < 4; ++ks) {
        const float* p = HHp + (size_t)s * DD + ks * 32 + g * 8;
        const f32x4 a = *(const f32x4*)p;
        const f32x4 bq = *(const f32x4*)(p + 4);
        he[ks] = (f32x4){a[0], a[2], bq[0], bq[2]};
        ho[ks] = (f32x4){a[1], a[3], bq[1], bq[3]};
    }

    // build A1 fragments (lane (g,li) holds neighbor bt*16+li, dims ks*32+g*8..+8)
    bf16x8 afr[4][4];
#pragma unroll
    for (int bt = 0; bt < 4; ++bt) {
        const unsigned short* pr = relPb + ((size_t)rr4[bt] << 7) + (g << 3);
#pragma unroll
        for (int ks = 0; ks < 4; ++ks) {
            const u32x4 pw = *(const u32x4*)(pr + (ks << 5));
            f32x4 pe, po;
#pragma unroll
            for (int j = 0; j < 4; ++j) {
                pe[j] = __uint_as_float(pw[j] << 16);
                po[j] = __uint_as_float(pw[j] & 0xffff0000u);
            }
            pe += he[ks];
            po += ho[ks];
#pragma unroll
            for (int j = 0; j < 4; ++j) {
                afr[bt][ks][2 * j]     = (__bf16)fmaxf(pe[j], 0.f);
                afr[bt][ks][2 * j + 1] = (__bf16)fmaxf(po[j], 0.f);
            }
        }
    }

    __syncthreads();

    // GEMM2 swapped: D[e, k_n] = Wa2 . A1^T; fuse Wa3-dot lane-locally.
    f32x4 pd2 = {};
    const int wrow = li << 7;  // li*128 u16
#pragma unroll
    for (int nt = 0; nt < 8; ++nt) {
        bf16x8 bfr[4];
#pragma unroll
        for (int ks = 0; ks < 4; ++ks)
            bfr[ks] = *(const bf16x8*)(&WL[(nt << 11) + wrow + (((ks * 4 + g) ^ li) << 3)]);
        const f32x4 w3f = *(const f32x4*)(Wa3 + nt * 16 + g * 4);
        f32x4 acc[4] = {};
#pragma unroll
        for (int ks = 0; ks < 4; ++ks)
#pragma unroll
            for (int bt = 0; bt < 4; ++bt) acc[bt] = mfma16(bfr[ks], afr[bt][ks], acc[bt]);
#pragma unroll
        for (int bt = 0; bt < 4; ++bt) {
            pd2[bt] += fmaxf(acc[bt][0], 0.f) * w3f[0] + fmaxf(acc[bt][1], 0.f) * w3f[1] +
                       fmaxf(acc[bt][2], 0.f) * w3f[2] + fmaxf(acc[bt][3], 0.f) * w3f[3];
        }
    }

    // ---- ISSUE tail gathers now (addresses independent of softmax) ----
    bf16x8 tv[16];
#pragma unroll
    for (int mt = 0; mt < 4; ++mt)
#pragma unroll
        for (int i = 0; i < 4; ++i) {
            const int r = mt * 16 + g * 4 + i;
            const int ti = __shfl(tIr, r);
            tv[mt * 4 + i] = *(const bf16x8*)(entB + (size_t)ti * DD + li * 8);
        }

    // reduce over g (rows split across g) -> every lane holds a3[k=bt*16+li]
#pragma unroll
    for (int bt = 0; bt < 4; ++bt) {
        pd2[bt] += __shfl_xor(pd2[bt], 16);
        pd2[bt] += __shfl_xor(pd2[bt], 32);
    }

    // softmax over sigmoid(a3); sigmoid in (0,1) -> no max needed
    float avn[4];
    float sm = 0.f;
#pragma unroll
    for (int bt = 0; bt < 4; ++bt) {
        avn[bt] = __expf(sigmoidf(pd2[bt]));
        sm += avn[bt];
    }
#pragma unroll
    for (int off = 1; off < 16; off <<= 1) sm += __shfl_xor(sm, off);
    const float inv = 1.f / sm;
    float ws4[4];
#pragma unroll
    for (int bt = 0; bt < 4; ++bt) ws4[bt] = avn[bt] * inv;

    // ---- CONSUME prefetched rows ----
    float s8[8] = {0.f};
#pragma unroll
    for (int mt = 0; mt < 4; ++mt)
#pragma unroll
        for (int i = 0; i < 4; ++i) {
            const float wt = __shfl(ws4[mt], g * 4 + i);
            const bf16x8 t8 = tv[mt * 4 + i];
#pragma unroll
            for (int j = 0; j < 8; ++j) s8[j] += wt * (float)t8[j];
        }
#pragma unroll
    for (int j = 0; j < 8; ++j) {
        s8[j] += __shfl_xor(s8[j], 16);
        s8[j] += __shfl_xor(s8[j], 32);
    }
    if (lane < 16) {
        union { bf16x8 v; unsigned short u[8]; } sv;
#pragma unroll
        for (int j = 0; j < 8; ++j) sv.u[j] = f2bf(s8[j]);
        *(bf16x8*)(s_bf + (size_t)s * DD + li * 8) = sv.v;
    }
}

// ---------------- heads + aggregator + FINAL, fused ----------------
// 512 blocks, 256 threads. Block handles 16 samples x 3 branches (48 rows);
// branch == mt-tile, so max/dot/sigmoid finishes in-block. No agg_ws.

__global__ __launch_bounds__(256, 2) void head_agg3(
    const int* __restrict__ u1, const int* __restrict__ u2, const int* __restrict__ cI,
    const unsigned short* __restrict__ s_bf, const unsigned short* __restrict__ entB,
    const unsigned short* __restrict__ Wxb, const float* __restrict__ bx,
    const unsigned short* __restrict__ W1b, const float* __restrict__ b1,
    const unsigned short* __restrict__ W2b, const float* __restrict__ b2,
    float* __restrict__ out) {
    constexpr int SBS = 136, HS = 132, YS = 264;
    __shared__ __align__(16) unsigned short SB[48 * SBS];
    __shared__ __align__(16) unsigned short HLb[48 * HS];
    __shared__ __align__(16) unsigned short Y1[48 * YS];
    __shared__ __align__(16) unsigned short Y2[48 * YS];
    __shared__ unsigned short bxl[256], b1l[256], b2l[256];
    __shared__ int eL[48];
    __shared__ float prr[4][16];

    const int t = threadIdx.x;
    const int lane = t & 63, w = t >> 6;
    const int g = lane >> 4, li = lane & 15;
    const int m0 = blockIdx.x * 16;

    if (t < 48) {
        const int br = t >> 4, j = t & 15;
        eL[t] = (br == 0 ? u1 : br == 1 ? u2 : cI)[m0 + j];
    }
    bxl[t] = f2bf(bx[t]); b1l[t] = f2bf(b1[t]); b2l[t] = f2bf(b2[t]);
    __syncthreads();

    // stage SB (attention sums) and HLb (renormed h) for 48 rows
    for (int idx = t; idx < 3072; idx += 256) {
        const int row = idx >> 6, cc = idx & 63;
        const int br = row >> 4, j = row & 15;
        const size_t sidx = (size_t)br * BB + m0 + j;
        *(unsigned int*)&SB[row * SBS + cc * 2] =
            ((const unsigned int*)(s_bf + sidx * DD))[cc];
        *(unsigned int*)&HLb[row * HS + cc * 2] =
            ((const unsigned int*)(entB + (size_t)eL[row] * DD))[cc];
    }
    __syncthreads();

    // heads: [48][256] = S[48][128] @ WxFlat^T  (mt = branch)
    f32x4 ah[3][4] = {};
#pragma unroll
    for (int ks = 0; ks < 4; ++ks) {
        const int kb = ks * 32 + g * 8;
        bf16x8 bb[4];
#pragma unroll
        for (int ntl = 0; ntl < 4; ++ntl)
            bb[ntl] = *(const bf16x8*)(Wxb + ((size_t)(w * 4 + ntl) * 16 + li) * DD + kb);
#pragma unroll
        for (int mt = 0; mt < 3; ++mt) {
            const bf16x8 a = *(const bf16x8*)(&SB[(mt * 16 + li) * SBS + kb]);
#pragma unroll
            for (int ntl = 0; ntl < 4; ++ntl) ah[mt][ntl] = mfma16(a, bb[ntl], ah[mt][ntl]);
        }
    }
#pragma unroll
    for (int mt = 0; mt < 3; ++mt)
#pragma unroll
        for (int ntl = 0; ntl < 4; ++ntl) {
            const int col = (w * 4 + ntl) * 16 + li;
            const int ee = col & 127;
#pragma unroll
            for (int i = 0; i < 4; ++i) {
                const int row = mt * 16 + g * 4 + i;
                const float v = ah[mt][ntl][i] + bf2f(bxl[col]);
                const float vec = leakyf(v);
                const float hvv = bf2f(HLb[row * HS + ee]);
                Y1[row * YS + col] = f2bf(hvv + vec);
                Y2[row * YS + col] = f2bf(hvv * vec);
            }
        }
    __syncthreads();

    f32x4 ac1[3][4] = {}, ac2[3][4] = {};
#pragma unroll
    for (int ks = 0; ks < 8; ++ks) {
        const int kb = ks * 32 + g * 8;
        bf16x8 bb1[4], bb2[4];
#pragma unroll
        for (int ntl = 0; ntl < 4; ++ntl) {
            bb1[ntl] = *(const bf16x8*)(W1b + ((size_t)(w * 4 + ntl) * 16 + li) * 256 + kb);
            bb2[ntl] = *(const bf16x8*)(W2b + ((size_t)(w * 4 + ntl) * 16 + li) * 256 + kb);
        }
#pragma unroll
        for (int mt = 0; mt < 3; ++mt) {
            const bf16x8 a1 = *(const bf16x8*)(&Y1[(mt * 16 + li) * YS + kb]);
            const bf16x8 a2 = *(const bf16x8*)(&Y2[(mt * 16 + li) * YS + kb]);
#pragma unroll
            for (int ntl = 0; ntl < 4; ++ntl) {
                ac1[mt][ntl] = mfma16(a1, bb1[ntl], ac1[mt][ntl]);
                ac2[mt][ntl] = mfma16(a2, bb2[ntl], ac2[mt][ntl]);
            }
        }
    }

    // agg-part of final dot: thread holds sample j=g*4+i, branch mt, 4 cols
    float part[4] = {0.f, 0.f, 0.f, 0.f};
#pragma unroll
    for (int ntl = 0; ntl < 4; ++ntl) {
        const int col = (w * 4 + ntl) * 16 + li;
        const float bb1v = bf2f(b1l[col]), bb2v = bf2f(b2l[col]);
#pragma unroll
        for (int i = 0; i < 4; ++i) {
            const float x0 = leakyf(ac1[0][ntl][i] + bb1v) + leakyf(ac2[0][ntl][i] + bb2v);
            const float x1 = leakyf(ac1[1][ntl][i] + bb1v) + leakyf(ac2[1][ntl][i] + bb2v);
            const float x2 = leakyf(ac1[2][ntl][i] + bb1v) + leakyf(ac2[2][ntl][i] + bb2v);
            part[i] += fmaxf(x0, x1) * x2;
        }
    }
#pragma unroll
    for (int off = 1; off < 16; off <<= 1)
#pragma unroll
        for (int i = 0; i < 4; ++i) part[i] += __shfl_xor(part[i], off);
    if (li == 0) {
#pragma unroll
        for (int i = 0; i < 4; ++i) prr[w][g * 4 + i] = part[i];
    }
    __syncthreads();

    // h-part + combine: 16 threads per sample j (t = j*16 + (t&15))
    {
        const int j = t >> 4, dl = (t & 15) * 8;
        const unsigned short* h1p = &HLb[(0 * 16 + j) * HS + dl];
        const unsigned short* h2p = &HLb[(1 * 16 + j) * HS + dl];
        const unsigned short* hcp = &HLb[(2 * 16 + j) * HS + dl];
        float a = 0.f;
#pragma unroll
        for (int jj = 0; jj < 8; ++jj)
            a += fmaxf(bf2f(h1p[jj]), bf2f(h2p[jj])) * bf2f(hcp[jj]);
#pragma unroll
        for (int off = 1; off < 16; off <<= 1) a += __shfl_xor(a, off);
        if ((t & 15) == 0) {
            const float tot = prr[0][j] + prr[1][j] + prr[2][j] + prr[3][j] + a;
            out[m0 + j] = sigmoidf(tot);
        }
    }
}

// ---------------- launcher ----------------

extern "C" void kernel_launch(void* const* d_in, const int* in_sizes, int n_in,
                              void* d_out, int out_size, void* d_ws, size_t ws_size,
                              hipStream_t stream) {
    (void)in_sizes; (void)n_in; (void)out_size; (void)ws_size;
    const int*   u1   = (const int*)d_in[0];
    const int*   u2   = (const int*)d_in[1];
    const int*   cI   = (const int*)d_in[2];
    const int*   adjE = (const int*)d_in[3];
    const int*   adjR = (const int*)d_in[4];
    const float* entE = (const float*)d_in[5];
    const float* relE = (const float*)d_in[6];
    const float* Wa1  = (const float*)d_in[7];
    const float* Wa2  = (const float*)d_in[8];
    const float* Wa3  = (const float*)d_in[9];
    const float* Wx   = (const float*)d_in[10];
    const float* bx   = (const float*)d_in[11];
    const float* W1   = (const float*)d_in[12];
    const float* b1   = (const float*)d_in[13];
    const float* W2   = (const float*)d_in[14];
    const float* b2   = (const float*)d_in[15];
    float* out = (float*)d_out;

    char* ws = (char*)d_ws;
    unsigned short* entB = (unsigned short*)(ws);              // 25,600,000 B
    unsigned short* Wa1b = (unsigned short*)(ws + 25600000);   //     65,536 B
    unsigned short* Wa2b = (unsigned short*)(ws + 25665536);   //     32,768 B
    unsigned short* Wxb  = (unsigned short*)(ws + 25698304);   //     65,536 B
    unsigned short* W1b  = (unsigned short*)(ws + 25763840);   //    131,072 B
    unsigned short* W2b  = (unsigned short*)(ws + 25894912);   //    131,072 B
    unsigned short* relPb = (unsigned short*)(ws + 26025984);  //     25,600 B
    float* HHp   = (float*)(ws + 26051584);                    // 12,582,912 B
    unsigned short* s_bf = (unsigned short*)(ws + 44925952);   //  6,291,456 B
    // total 51,217,408 B

    hipLaunchKernelGGL(prep_emb, dim3(NENT / 4), dim3(256), 0, stream, entE, entB, NENT);
    hipLaunchKernelGGL(prep_w, dim3(832), dim3(256), 0, stream, Wa1, Wa2, Wx, W1, W2,
                       Wa1b, Wa2b, Wxb, W1b, W2b);
    hipLaunchKernelGGL(relp_k, dim3(NREL), dim3(128), 0, stream, relE, Wa1, relPb);
    hipLaunchKernelGGL(hh_gemm, dim3(3 * BB / 64), dim3(256), 0, stream,
                       u1, u2, cI, entB, Wa1b, HHp);
    hipLaunchKernelGGL(attn_tail, dim3(3 * BB / 8), dim3(512), 0, stream,
                       u1, u2, cI, adjE, adjR, entB, relPb, Wa2b, Wa3, HHp, s_bf);
    hipLaunchKernelGGL(head_agg3, dim3(BB / 16), dim3(256), 0, stream,
                       u1, u2, cI, s_bf, entB, Wxb, bx, W1b, b1, W2b, b2, out);
}